// Round 16
// baseline (319.325 us; speedup 1.0000x reference)
//
#include <hip/hip_runtime.h>

// LSTM round 16: R10 frame verbatim (8 batches/wave, 1024 waves = 1/SIMD, f16
// MFMA, pipelined chain-1, bpermute h-exchange, no LDS tiles, no barriers).
// Single change: gate nonlinearities via f16 transcendentals (v_exp_f16 /
// v_rcp_f16) — probe of f16-trans occupancy. sigma/tanh saturation exact.

typedef __attribute__((ext_vector_type(8))) _Float16 half8;
typedef __attribute__((ext_vector_type(4))) float f32x4;
typedef __attribute__((ext_vector_type(4))) unsigned int u32x4;

static constexpr int BB  = 8192;
static constexpr int TT  = 512;
static constexpr int NIN = 5;
static constexpr int HH  = 32;

__device__ __forceinline__ unsigned short f16b(float f) {
    _Float16 h = (_Float16)f;                       // RNE
    return __builtin_bit_cast(unsigned short, h);
}

// sigmoid(x) = 1/(1 + exp2(-log2e * x)), f16 exp/rcp path
__device__ __forceinline__ float sig16(float x) {
    float xm = -1.4426950408889634f * x;
    unsigned int t, e, s, r;
    float out;
    asm("v_cvt_f16_f32 %0, %1" : "=v"(t) : "v"(xm));
    asm("v_exp_f16 %0, %1"     : "=v"(e) : "v"(t));
    asm("v_add_f16 %0, %1, 1.0" : "=v"(s) : "v"(e));
    asm("v_rcp_f16 %0, %1"     : "=v"(r) : "v"(s));
    asm("v_cvt_f32_f16 %0, %1" : "=v"(out) : "v"(r));
    return out;
}
// tanh(x) = 1 - 2/(1 + exp2(2*log2e*x)), f16 exp/rcp path
__device__ __forceinline__ float th16(float x) {
    float xm = 2.8853900817779268f * x;
    unsigned int t, e, s, r;
    float rv;
    asm("v_cvt_f16_f32 %0, %1" : "=v"(t) : "v"(xm));
    asm("v_exp_f16 %0, %1"     : "=v"(e) : "v"(t));
    asm("v_add_f16 %0, %1, 1.0" : "=v"(s) : "v"(e));
    asm("v_rcp_f16 %0, %1"     : "=v"(r) : "v"(s));
    asm("v_cvt_f32_f16 %0, %1" : "=v"(rv) : "v"(r));
    return fmaf(-2.0f, rv, 1.0f);
}

__global__ __launch_bounds__(64) void lstm_t16(
    const float* __restrict__ x,     // [B, T, 5]
    const float* __restrict__ W_ih,  // [128, 5]
    const float* __restrict__ W_hh,  // [128, 32]
    const float* __restrict__ b_ih,  // [128]
    const float* __restrict__ b_hh,  // [128]
    const float* __restrict__ W_fc,  // [1, 32]
    const float* __restrict__ b_fc,  // [1]
    float* __restrict__ out)         // [B]
{
    const int lane = threadIdx.x & 63;
    const int col  = lane & 15;      // batch (dup x2)
    const int kg   = lane >> 4;      // k-group
    const int b0   = blockIdx.x * 8;
    const int bloc = col & 7;
    const bool jlow = (col < 8);
    const int jbase = 4 * kg + (jlow ? 0 : 16);

    // ---- A-fragments (loop-invariant). Tile t4: gate rows gr=16*t4+col,
    // k=kg*8+e. Ahh: W_hh@f16. Ax (kg0 only): slots0-4=W_ih@f16,
    // slot5=bias_hi, slot6=bias_lo, slot7=0; kg1-3 zero.
    half8 Ahh[8], Ax[8];
#pragma unroll
    for (int t4 = 0; t4 < 8; ++t4) {
        const int gr = 16 * t4 + col;
#pragma unroll
        for (int e = 0; e < 8; ++e)
            Ahh[t4][e] = (_Float16)W_hh[gr * HH + kg * 8 + e];
        half8 v;
#pragma unroll
        for (int e = 0; e < 8; ++e) v[e] = (_Float16)0.f;
        if (kg == 0) {
#pragma unroll
            for (int e = 0; e < NIN; ++e) v[e] = (_Float16)W_ih[gr * NIN + e];
            float bias = b_ih[gr] + b_hh[gr];
            _Float16 bh_ = (_Float16)bias;
            v[5] = bh_;
            v[6] = (_Float16)(bias - (float)bh_);
        }
        Ax[t4] = v;
    }

    // ---- bh shuffle sources (R5/R10-verified mapping) ----
    const int srcA = 32 * (kg & 1) + bloc + 8 * (kg >> 1);
    const int srcB = srcA + 16;

    const bool xk = (kg == 0);

    // ---- x stream: per-lane loads of own batch row (8-lane broadcast) ----
    const float* px = x + (size_t)(b0 + bloc) * TT * NIN;
    float x0 = px[0], x1 = px[1], x2 = px[2], x3 = px[3], x4 = px[4];

    unsigned int bh0 = 0, bh1 = 0, bh2 = 0, bh3 = 0;   // h^T frag (h=0)
    float c0 = 0.f, c1 = 0.f, c2 = 0.f, c3 = 0.f;
    float h0 = 0.f, h1 = 0.f, h2 = 0.f, h3 = 0.f;
    const f32x4 z = {0.f, 0.f, 0.f, 0.f};

    auto make_bx = [&](float v0, float v1, float v2, float v3, float v4) -> half8 {
        unsigned w0 = (unsigned)f16b(v0) | ((unsigned)f16b(v1) << 16);
        unsigned w1 = (unsigned)f16b(v2) | ((unsigned)f16b(v3) << 16);
        unsigned w2 = (unsigned)f16b(v4) | (0x3C00u << 16);   // slot5 = 1.0
        unsigned w3 = 0x00003C00u;                            // slot6 = 1.0
        u32x4 u = {xk ? w0 : 0u, xk ? w1 : 0u, xk ? w2 : 0u, xk ? w3 : 0u};
        return __builtin_bit_cast(half8, u);
    };

    // ---- prologue: chain-1 for t=0 ----
    f32x4 accN[8];
    {
        half8 bx0 = make_bx(x0, x1, x2, x3, x4);
#pragma unroll
        for (int t4 = 0; t4 < 8; ++t4)
            accN[t4] = __builtin_amdgcn_mfma_f32_16x16x32_f16(Ax[t4], bx0, z, 0, 0, 0);
    }

#pragma unroll 1
    for (int t = 0; t < TT; ++t) {
        // (1) prefetch x(t+1)
        const size_t off = (size_t)((t + 1 < TT) ? (t + 1) : t) * NIN;
        float n0 = px[off + 0], n1 = px[off + 1], n2 = px[off + 2],
              n3 = px[off + 3], n4 = px[off + 4];

        // (2) chain-2: acc = Ahh*bh + accN
        u32x4 bhu = {bh0, bh1, bh2, bh3};
        half8 bh = __builtin_bit_cast(half8, bhu);
        f32x4 acc[8];
#pragma unroll
        for (int t4 = 0; t4 < 8; ++t4)
            acc[t4] = __builtin_amdgcn_mfma_f32_16x16x32_f16(Ahh[t4], bh, accN[t4], 0, 0, 0);

        // (3) chain-1 for t+1 (independent; fills cell-phase matrix idle)
        half8 bxn = make_bx(n0, n1, n2, n3, n4);
#pragma unroll
        for (int t4 = 0; t4 < 8; ++t4)
            accN[t4] = __builtin_amdgcn_mfma_f32_16x16x32_f16(Ax[t4], bxn, z, 0, 0, 0);

        // (4) 4 cells — f16 transcendental path
#pragma unroll
        for (int r = 0; r < 4; ++r) {
            float gi = jlow ? acc[0][r] : acc[1][r];
            float gf = jlow ? acc[2][r] : acc[3][r];
            float gg = jlow ? acc[4][r] : acc[5][r];
            float go = jlow ? acc[6][r] : acc[7][r];
            float iv = sig16(gi);
            float fv = sig16(gf);
            float gv = th16(gg);
            float ov = sig16(go);
            float cc = (r == 0 ? c0 : r == 1 ? c1 : r == 2 ? c2 : c3);
            cc = fmaf(fv, cc, iv * gv);
            float hh = ov * th16(cc);
            if (r == 0) { c0 = cc; h0 = hh; }
            else if (r == 1) { c1 = cc; h1 = hh; }
            else if (r == 2) { c2 = cc; h2 = hh; }
            else { c3 = cc; h3 = hh; }
        }

        // (5) pack h -> f16 pairs; rebuild bh for t+1 (4 shfl, R5 mapping)
        unsigned int p0 = (unsigned)f16b(h0) | ((unsigned)f16b(h1) << 16);
        unsigned int p1 = (unsigned)f16b(h2) | ((unsigned)f16b(h3) << 16);
        bh0 = (unsigned)__shfl((int)p0, srcA, 64);
        bh1 = (unsigned)__shfl((int)p1, srcA, 64);
        bh2 = (unsigned)__shfl((int)p0, srcB, 64);
        bh3 = (unsigned)__shfl((int)p1, srcB, 64);

        x0 = n0; x1 = n1; x2 = n2; x3 = n3; x4 = n4;
    }

    // ---- head: out[b] = sum_j h[b][j]*W_fc[j] + b_fc ----
    float v = h0 * W_fc[jbase + 0] + h1 * W_fc[jbase + 1]
            + h2 * W_fc[jbase + 2] + h3 * W_fc[jbase + 3];
    v += __shfl_xor(v, 8);
    v += __shfl_xor(v, 16);
    v += __shfl_xor(v, 32);
    if (lane < 8) out[b0 + lane] = v + b_fc[0];
}

extern "C" void kernel_launch(void* const* d_in, const int* in_sizes, int n_in,
                              void* d_out, int out_size, void* d_ws, size_t ws_size,
                              hipStream_t stream) {
    const float* x    = (const float*)d_in[0];
    const float* W_ih = (const float*)d_in[1];
    const float* W_hh = (const float*)d_in[2];
    const float* b_ih = (const float*)d_in[3];
    const float* b_hh = (const float*)d_in[4];
    const float* W_fc = (const float*)d_in[5];
    const float* b_fc = (const float*)d_in[6];
    float* out = (float*)d_out;

    lstm_t16<<<dim3(BB / 8), dim3(64), 0, stream>>>(
        x, W_ih, W_hh, b_ih, b_hh, W_fc, b_fc, out);
}

// Round 17
// 271.396 us; speedup vs baseline: 1.1766x; 1.1766x over previous
//
#include <hip/hip_runtime.h>

// LSTM FINAL (= round 10, best measured: 270 us, absmax 0.0039).
// B=8192, T=512, IN=5, H=32. 1024 blocks x 64 thr = 1 wave/SIMD exact fill.
// 8 batches/wave; transposed-gate MFMA (f16): gates_T[128][16 cols = 8 batches
// dup2] via 8 gate-tiles; chain-2 = mfma(Ahh, bh, accN) where accN (x-projection
// chain-1) was issued during the PREVIOUS step's cell phase (software pipeline).
// Lane owns 4 cells (all gates in-lane via acc regs); h feedback = pack to f16
// pairs + 4 ds_bpermute (DS pipe, hidden under VALU). No LDS tiles, no barriers.
// Rationale from 16 rounds of probes:
//  - 1 wave/SIMD, zero duplicated work is optimal: 2-wave topologies (R6/R7/R11),
//    in-wave ILP-2 (R8) all regressed — duplicated issue > latency hidden.
//  - v_exp/v_rcp beat polynomial (R9) and paired-rcp (R12) and f16-trans (R16).
//  - bpermute on DS pipe beats DPP+cndmask on VALU (R13).
//  - 4 cells/lane = theoretical minimum (B*H cells over all lanes at full fill).

typedef __attribute__((ext_vector_type(8))) _Float16 half8;
typedef __attribute__((ext_vector_type(4))) float f32x4;
typedef __attribute__((ext_vector_type(4))) unsigned int u32x4;

static constexpr int BB  = 8192;
static constexpr int TT  = 512;
static constexpr int NIN = 5;
static constexpr int HH  = 32;

__device__ __forceinline__ unsigned short f16b(float f) {
    _Float16 h = (_Float16)f;                       // RNE
    return __builtin_bit_cast(unsigned short, h);
}
__device__ __forceinline__ float fast_sigmoid(float x) {
    float e = __builtin_amdgcn_exp2f(-1.4426950408889634f * x);
    return __builtin_amdgcn_rcpf(1.0f + e);
}
__device__ __forceinline__ float fast_tanh(float x) {
    float e = __builtin_amdgcn_exp2f(2.8853900817779268f * x);
    return 1.0f - 2.0f * __builtin_amdgcn_rcpf(1.0f + e);
}

__global__ __launch_bounds__(64) void lstm_f16(
    const float* __restrict__ x,     // [B, T, 5]
    const float* __restrict__ W_ih,  // [128, 5]
    const float* __restrict__ W_hh,  // [128, 32]
    const float* __restrict__ b_ih,  // [128]
    const float* __restrict__ b_hh,  // [128]
    const float* __restrict__ W_fc,  // [1, 32]
    const float* __restrict__ b_fc,  // [1]
    float* __restrict__ out)         // [B]
{
    const int lane = threadIdx.x & 63;
    const int col  = lane & 15;      // batch (dup x2)
    const int kg   = lane >> 4;      // k-group
    const int b0   = blockIdx.x * 8;
    const int bloc = col & 7;
    const bool jlow = (col < 8);
    const int jbase = 4 * kg + (jlow ? 0 : 16);

    // ---- A-fragments (loop-invariant). Tile t4: gate rows gr=16*t4+col,
    // k=kg*8+e. Ahh: W_hh@f16. Ax (kg0 only): slots0-4=W_ih@f16,
    // slot5=bias_hi, slot6=bias_lo, slot7=0; kg1-3 zero.
    half8 Ahh[8], Ax[8];
#pragma unroll
    for (int t4 = 0; t4 < 8; ++t4) {
        const int gr = 16 * t4 + col;
#pragma unroll
        for (int e = 0; e < 8; ++e)
            Ahh[t4][e] = (_Float16)W_hh[gr * HH + kg * 8 + e];
        half8 v;
#pragma unroll
        for (int e = 0; e < 8; ++e) v[e] = (_Float16)0.f;
        if (kg == 0) {
#pragma unroll
            for (int e = 0; e < NIN; ++e) v[e] = (_Float16)W_ih[gr * NIN + e];
            float bias = b_ih[gr] + b_hh[gr];
            _Float16 bh_ = (_Float16)bias;
            v[5] = bh_;
            v[6] = (_Float16)(bias - (float)bh_);
        }
        Ax[t4] = v;
    }

    // ---- bh shuffle sources (verified mapping) ----
    const int srcA = 32 * (kg & 1) + bloc + 8 * (kg >> 1);
    const int srcB = srcA + 16;

    const bool xk = (kg == 0);

    // ---- x stream: per-lane loads of own batch row (8-lane broadcast) ----
    const float* px = x + (size_t)(b0 + bloc) * TT * NIN;
    float x0 = px[0], x1 = px[1], x2 = px[2], x3 = px[3], x4 = px[4];

    unsigned int bh0 = 0, bh1 = 0, bh2 = 0, bh3 = 0;   // h^T frag (h=0)
    float c0 = 0.f, c1 = 0.f, c2 = 0.f, c3 = 0.f;
    float h0 = 0.f, h1 = 0.f, h2 = 0.f, h3 = 0.f;
    const f32x4 z = {0.f, 0.f, 0.f, 0.f};

    auto make_bx = [&](float v0, float v1, float v2, float v3, float v4) -> half8 {
        unsigned w0 = (unsigned)f16b(v0) | ((unsigned)f16b(v1) << 16);
        unsigned w1 = (unsigned)f16b(v2) | ((unsigned)f16b(v3) << 16);
        unsigned w2 = (unsigned)f16b(v4) | (0x3C00u << 16);   // slot5 = 1.0
        unsigned w3 = 0x00003C00u;                            // slot6 = 1.0
        u32x4 u = {xk ? w0 : 0u, xk ? w1 : 0u, xk ? w2 : 0u, xk ? w3 : 0u};
        return __builtin_bit_cast(half8, u);
    };

    // ---- prologue: chain-1 for t=0 ----
    f32x4 accN[8];
    {
        half8 bx0 = make_bx(x0, x1, x2, x3, x4);
#pragma unroll
        for (int t4 = 0; t4 < 8; ++t4)
            accN[t4] = __builtin_amdgcn_mfma_f32_16x16x32_f16(Ax[t4], bx0, z, 0, 0, 0);
    }

#pragma unroll 1
    for (int t = 0; t < TT; ++t) {
        // (1) prefetch x(t+1)
        const size_t off = (size_t)((t + 1 < TT) ? (t + 1) : t) * NIN;
        float n0 = px[off + 0], n1 = px[off + 1], n2 = px[off + 2],
              n3 = px[off + 3], n4 = px[off + 4];

        // (2) chain-2: acc = Ahh*bh + accN
        u32x4 bhu = {bh0, bh1, bh2, bh3};
        half8 bh = __builtin_bit_cast(half8, bhu);
        f32x4 acc[8];
#pragma unroll
        for (int t4 = 0; t4 < 8; ++t4)
            acc[t4] = __builtin_amdgcn_mfma_f32_16x16x32_f16(Ahh[t4], bh, accN[t4], 0, 0, 0);

        // (3) chain-1 for t+1 (independent; fills cell-phase matrix idle)
        half8 bxn = make_bx(n0, n1, n2, n3, n4);
#pragma unroll
        for (int t4 = 0; t4 < 8; ++t4)
            accN[t4] = __builtin_amdgcn_mfma_f32_16x16x32_f16(Ax[t4], bxn, z, 0, 0, 0);

        // (4) 4 cells (exp/rcp form, saturation-exact)
#pragma unroll
        for (int r = 0; r < 4; ++r) {
            float gi = jlow ? acc[0][r] : acc[1][r];
            float gf = jlow ? acc[2][r] : acc[3][r];
            float gg = jlow ? acc[4][r] : acc[5][r];
            float go = jlow ? acc[6][r] : acc[7][r];
            float iv = fast_sigmoid(gi);
            float fv = fast_sigmoid(gf);
            float gv = fast_tanh(gg);
            float ov = fast_sigmoid(go);
            float cc = (r == 0 ? c0 : r == 1 ? c1 : r == 2 ? c2 : c3);
            cc = fmaf(fv, cc, iv * gv);
            float hh = ov * fast_tanh(cc);
            if (r == 0) { c0 = cc; h0 = hh; }
            else if (r == 1) { c1 = cc; h1 = hh; }
            else if (r == 2) { c2 = cc; h2 = hh; }
            else { c3 = cc; h3 = hh; }
        }

        // (5) pack h -> f16 pairs; rebuild bh for t+1 (4 bpermute, DS pipe)
        unsigned int p0 = (unsigned)f16b(h0) | ((unsigned)f16b(h1) << 16);
        unsigned int p1 = (unsigned)f16b(h2) | ((unsigned)f16b(h3) << 16);
        bh0 = (unsigned)__shfl((int)p0, srcA, 64);
        bh1 = (unsigned)__shfl((int)p1, srcA, 64);
        bh2 = (unsigned)__shfl((int)p0, srcB, 64);
        bh3 = (unsigned)__shfl((int)p1, srcB, 64);

        x0 = n0; x1 = n1; x2 = n2; x3 = n3; x4 = n4;
    }

    // ---- head: out[b] = sum_j h[b][j]*W_fc[j] + b_fc ----
    float v = h0 * W_fc[jbase + 0] + h1 * W_fc[jbase + 1]
            + h2 * W_fc[jbase + 2] + h3 * W_fc[jbase + 3];
    v += __shfl_xor(v, 8);
    v += __shfl_xor(v, 16);
    v += __shfl_xor(v, 32);
    if (lane < 8) out[b0 + lane] = v + b_fc[0];
}

extern "C" void kernel_launch(void* const* d_in, const int* in_sizes, int n_in,
                              void* d_out, int out_size, void* d_ws, size_t ws_size,
                              hipStream_t stream) {
    const float* x    = (const float*)d_in[0];
    const float* W_ih = (const float*)d_in[1];
    const float* W_hh = (const float*)d_in[2];
    const float* b_ih = (const float*)d_in[3];
    const float* b_hh = (const float*)d_in[4];
    const float* W_fc = (const float*)d_in[5];
    const float* b_fc = (const float*)d_in[6];
    float* out = (float*)d_out;

    lstm_f16<<<dim3(BB / 8), dim3(64), 0, stream>>>(
        x, W_ih, W_hh, b_ih, b_hh, W_fc, b_fc, out);
}